// Round 18
// baseline (381.274 us; speedup 1.0000x reference)
//
#include <hip/hip_runtime.h>

typedef unsigned short u16;
typedef unsigned int u32;
typedef unsigned long long u64;
typedef _Float16 f16;
typedef __attribute__((ext_vector_type(8))) _Float16 half8;
typedef __attribute__((ext_vector_type(4))) float f32x4;

#define HW 2304
#define CC 1024
#define DD 256
#define NB 4
#define CANDCAP 256
#define RANKC 33
#define GATE 0.099f

// Strict IEEE f32 ops the compiler cannot contract into FMA (selection path only).
__device__ __forceinline__ float mul_s(float a, float b) {
  float r; asm("v_mul_f32 %0, %1, %2" : "=v"(r) : "v"(a), "v"(b)); return r;
}
__device__ __forceinline__ float add_s(float a, float b) {
  float r; asm("v_add_f32 %0, %1, %2" : "=v"(r) : "v"(a), "v"(b)); return r;
}
// 2-term fp16 split: x ≈ hi + lo, error ~2^-22 relative.
__device__ __forceinline__ void split16(float a, u16& hi, u16& lo) {
  f16 h = (f16)a;
  float hf = (float)h;
  f16 l = (f16)(a - hf);
  __builtin_memcpy(&hi, &h, 2);
  __builtin_memcpy(&lo, &l, 2);
}

// ---------------- kernel 0: weights -> fp16 hi/lo ----------------
__global__ void prep_weights(const float* __restrict__ wq, const float* __restrict__ wk,
                             const float* __restrict__ wv, const float* __restrict__ wo,
                             u16* __restrict__ qh, u16* __restrict__ ql,
                             u16* __restrict__ kh, u16* __restrict__ kl,
                             u16* __restrict__ vh, u16* __restrict__ vl,
                             u16* __restrict__ oh, u16* __restrict__ ol) {
  int idx = blockIdx.x * 256 + threadIdx.x;
  for (int i = idx; i < 4 * 262144; i += 262144) {
    int which = i >> 18, loc = i & 262143;
    const float* s = (which == 0) ? wq : (which == 1) ? wk : (which == 2) ? wv : wo;
    u16* dh = (which == 0) ? qh : (which == 1) ? kh : (which == 2) ? vh : oh;
    u16* dl = (which == 0) ? ql : (which == 1) ? kl : (which == 2) ? vl : ol;
    u16 h, l; split16(s[loc], h, l);
    dh[loc] = h; dl[loc] = l;
  }
}

// ---------------- kernel 1: ray preprocessing (strict IEEE, numpy-faithful) ----------------
__global__ void prep_rays(const float* __restrict__ pq, const float* __restrict__ pk,
                          float* __restrict__ qray, float* __restrict__ kray) {
#pragma clang fp contract(off)
  int t = blockIdx.x * 256 + threadIdx.x;
  const float* src = blockIdx.y ? pk : pq;
  float* dst = blockIdx.y ? kray : qray;
  int b = t / HW, i = t % HW;
  const float* sp = src + (size_t)b * 6 * HW + i;
  float d0 = sp[0], d1 = sp[HW], d2 = sp[2 * HW];
  float m0 = sp[3 * HW], m1 = sp[4 * HW], m2 = sp[5 * HW];
  float nd = __fsqrt_rn(add_s(add_s(mul_s(d0, d0), mul_s(d1, d1)), mul_s(d2, d2)));
  float nc = fmaxf(nd, 1e-6f);
  float ix = d0 / nc, iy = d1 / nc, iz = d2 / nc;
  float nm = __fsqrt_rn(add_s(add_s(mul_s(m0, m0), mul_s(m1, m1)), mul_s(m2, m2)));
  float4* dp = (float4*)(dst + (size_t)t * 12);
  dp[0] = make_float4(m0, m1, m2, nm);
  dp[1] = make_float4(ix, iy, iz, 0.f);
  dp[2] = make_float4(d0, d1, d2, 0.f);
}

// ---------------- kernel 2: LayerNorm stats ----------------
__global__ __launch_bounds__(256) void ln_stats(const float* __restrict__ qmap,
                                                const float* __restrict__ kvmap,
                                                float* __restrict__ mu_q, float* __restrict__ rs_q,
                                                float* __restrict__ mu_k, float* __restrict__ rs_k) {
  const float* src = blockIdx.z ? kvmap : qmap;
  float* mu = blockIdx.z ? mu_k : mu_q;
  float* rs = blockIdx.z ? rs_k : rs_q;
  int b = blockIdx.y;
  int i0 = blockIdx.x * 32;
  int lane = threadIdx.x & 31, strip = threadIdx.x >> 5;
  const float* p = src + (size_t)b * CC * HW + i0 + lane;
  float s = 0.f, s2 = 0.f;
  for (int c = strip; c < CC; c += 8) {
    float v = p[(size_t)c * HW];
    s += v; s2 += v * v;
  }
  __shared__ float rsum[8][32], rsq[8][32];
  rsum[strip][lane] = s; rsq[strip][lane] = s2;
  __syncthreads();
  if (threadIdx.x < 32) {
    float ts = 0.f, tq = 0.f;
    for (int k = 0; k < 8; ++k) { ts += rsum[k][lane]; tq += rsq[k][lane]; }
    float m = ts * (1.f / 1024.f);
    float var = fmaxf(tq * (1.f / 1024.f) - m * m, 0.f);
    mu[b * HW + i0 + lane] = m;
    rs[b * HW + i0 + lane] = rsqrtf(var + 1e-5f);
  }
}

// ---------------- kernel 3: LN + QKV projection, split-fp16 MFMA ----------------
__global__ __launch_bounds__(256) void proj_mfma(
    const float* __restrict__ qmap, const float* __restrict__ kvmap,
    const float* __restrict__ gq, const float* __restrict__ bgq,
    const float* __restrict__ gk, const float* __restrict__ bgk,
    const u16* __restrict__ wqh, const u16* __restrict__ wql,
    const u16* __restrict__ wkh, const u16* __restrict__ wkl,
    const u16* __restrict__ wvh, const u16* __restrict__ wvl,
    const float* __restrict__ bq, const float* __restrict__ bk, const float* __restrict__ bv,
    const float* __restrict__ muq, const float* __restrict__ rsq,
    const float* __restrict__ muk, const float* __restrict__ rsk,
    float* __restrict__ qf, float* __restrict__ kf, float* __restrict__ vf) {
  int mtile = blockIdx.x, proj = blockIdx.y, b = blockIdx.z;
  int i0 = mtile * 64;
  const float* A; const u16* Wh; const u16* Wl;
  const float* gamma; const float* beta; const float* mup; const float* rsp; const float* bias;
  float* outp;
  if (proj == 0)      { A = qmap;  Wh = wqh; Wl = wql; gamma = gq; beta = bgq; mup = muq; rsp = rsq; bias = bq; outp = qf; }
  else if (proj == 1) { A = kvmap; Wh = wkh; Wl = wkl; gamma = gk; beta = bgk; mup = muk; rsp = rsk; bias = bk; outp = kf; }
  else                { A = kvmap; Wh = wvh; Wl = wvl; gamma = nullptr; beta = nullptr; mup = nullptr; rsp = nullptr; bias = bv; outp = vf; }
  __shared__ u16 Ah[64 * 72], Al[64 * 72];
  __shared__ float mul[64], rsl[64];
  int tid = threadIdx.x;
  int lane = tid & 63, wid = tid >> 6;
  if (proj < 2 && tid < 64) {
    mul[tid] = mup[b * HW + i0 + tid];
    rsl[tid] = rsp[b * HW + i0 + tid];
  }
  __syncthreads();
  f32x4 acc[4][4] = {};
  int c_loc = tid >> 2;
  int i4 = (tid & 3) * 4;
  int rowA = lane & 15, kch = (lane >> 4) * 8;
  for (int ks = 0; ks < 16; ++ks) {
    int c0 = ks * 64;
    float gma = 1.f, bet = 0.f;
    if (proj < 2) { gma = gamma[c0 + c_loc]; bet = beta[c0 + c_loc]; }
    const float* ap = A + ((size_t)(b * CC + c0 + c_loc)) * HW + i0;
#pragma unroll
    for (int p = 0; p < 4; ++p) {
      int ib = p * 16 + i4;
      float4 v = *(const float4*)(ap + ib);
      float e0 = v.x, e1 = v.y, e2 = v.z, e3 = v.w;
      if (proj < 2) {
        e0 = (e0 - mul[ib + 0]) * rsl[ib + 0] * gma + bet;
        e1 = (e1 - mul[ib + 1]) * rsl[ib + 1] * gma + bet;
        e2 = (e2 - mul[ib + 2]) * rsl[ib + 2] * gma + bet;
        e3 = (e3 - mul[ib + 3]) * rsl[ib + 3] * gma + bet;
      }
      u16 h, l;
      split16(e0, h, l); Ah[(ib + 0) * 72 + c_loc] = h; Al[(ib + 0) * 72 + c_loc] = l;
      split16(e1, h, l); Ah[(ib + 1) * 72 + c_loc] = h; Al[(ib + 1) * 72 + c_loc] = l;
      split16(e2, h, l); Ah[(ib + 2) * 72 + c_loc] = h; Al[(ib + 2) * 72 + c_loc] = l;
      split16(e3, h, l); Ah[(ib + 3) * 72 + c_loc] = h; Al[(ib + 3) * 72 + c_loc] = l;
    }
    __syncthreads();
#pragma unroll
    for (int kk = 0; kk < 2; ++kk) {
      int ko = kk * 32 + kch;
      half8 ah[4], al[4], bh[4], bl[4];
#pragma unroll
      for (int mf = 0; mf < 4; ++mf) {
        ah[mf] = *(const half8*)&Ah[(mf * 16 + rowA) * 72 + ko];
        al[mf] = *(const half8*)&Al[(mf * 16 + rowA) * 72 + ko];
      }
#pragma unroll
      for (int nf = 0; nf < 4; ++nf) {
        size_t woff = (size_t)(wid * 64 + nf * 16 + rowA) * CC + c0 + ko;
        bh[nf] = *(const half8*)&Wh[woff];
        bl[nf] = *(const half8*)&Wl[woff];
      }
#pragma unroll
      for (int mf = 0; mf < 4; ++mf)
#pragma unroll
        for (int nf = 0; nf < 4; ++nf) {
          acc[mf][nf] = __builtin_amdgcn_mfma_f32_16x16x32_f16(ah[mf], bh[nf], acc[mf][nf], 0, 0, 0);
          acc[mf][nf] = __builtin_amdgcn_mfma_f32_16x16x32_f16(ah[mf], bl[nf], acc[mf][nf], 0, 0, 0);
          acc[mf][nf] = __builtin_amdgcn_mfma_f32_16x16x32_f16(al[mf], bh[nf], acc[mf][nf], 0, 0, 0);
        }
    }
    __syncthreads();
  }
  int r4 = (lane >> 4) * 4, cold = lane & 15;
#pragma unroll
  for (int nf = 0; nf < 4; ++nf) {
    int dcol = wid * 64 + nf * 16 + cold;
    float bsv = bias[dcol];
#pragma unroll
    for (int mf = 0; mf < 4; ++mf) {
#pragma unroll
      for (int r = 0; r < 4; ++r) {
        int irow = i0 + mf * 16 + r4 + r;
        outp[(size_t)(b * HW + irow) * DD + dcol] = acc[mf][nf][r] + bsv;
      }
    }
  }
}

// ---------------- kernel 4: top-33 + hedge attention, XCD-swizzled + coalesced logits ------
__global__ __launch_bounds__(64) void attn_f32(
    const float* __restrict__ qf, const float* __restrict__ kf, const float* __restrict__ vf,
    const float* __restrict__ qray, const float* __restrict__ kray,
    float* __restrict__ fusedf, float* __restrict__ dfused, int* __restrict__ flags) {
#pragma clang fp contract(off)
  // XCD-contiguous swizzle (bijective: 9216 % 8 == 0). Each XCD owns a contiguous
  // half-batch of query rows -> its kf/vf gather neighborhood stays L2-hot.
  int flat = blockIdx.y * HW + blockIdx.x;
  int swz = (flat & 7) * ((NB * HW) / 8) + (flat >> 3);
  int b = swz / HW, i = swz - b * HW;
  int lane = threadIdx.x;
  __shared__ u32 hist[1024];
  __shared__ int kidx[RANKC];
  __shared__ float kr[RANKC];
  __shared__ float lgt[RANKC];
  __shared__ float wgt[RANKC];
  __shared__ float dw[RANKC];
  __shared__ int cidx[CANDCAP];
  __shared__ float cr[CANDCAP];
  __shared__ int s_alt, s_last, s_hedge;
  int tok = b * HW + i;
  float4 qreg = ((const float4*)(qf + (size_t)tok * DD))[lane];
  const float* qp = qray + (size_t)tok * 12;
  float4 mq = ((const float4*)qp)[0];
  float4 dq = ((const float4*)qp)[1];
#pragma unroll
  for (int k = 0; k < 16; ++k) hist[lane * 16 + k] = 0;
  __syncthreads();
  const float* krb = kray + (size_t)b * HW * 12;
  auto rcomp = [&](int j) -> float {
    const float4* kp4 = (const float4*)(krb + (size_t)j * 12);
    float4 km = kp4[0], kd = kp4[1];
    float p0 = mul_s(dq.x, km.x), p1 = mul_s(dq.y, km.y), p2 = mul_s(dq.z, km.z);
    float s1 = add_s(add_s(p0, p2), p1);
    float q0 = mul_s(kd.x, mq.x), q1 = mul_s(kd.y, mq.y), q2 = mul_s(kd.z, mq.z);
    float s2 = add_s(add_s(q0, q2), q1);
    float num = fabsf(add_s(s1, s2));
    float den = add_s(add_s(mq.w, km.w), 1e-6f);
    return num / den;
  };
  float rreg[36];
#pragma unroll
  for (int t = 0; t < 36; ++t) {
    rreg[t] = rcomp(t * 64 + lane);
    atomicAdd(&hist[__float_as_uint(rreg[t]) >> 22], 1u);
  }
  __syncthreads();
  int own = 0;
#pragma unroll
  for (int k = 0; k < 16; ++k) own += (int)hist[lane * 16 + k];
  int incl = own;
  for (int off = 1; off < 64; off <<= 1) {
    int nn = __shfl_up(incl, off);
    if (lane >= off) incl += nn;
  }
  u64 bal = __ballot(incl >= RANKC);
  int srcl = __ffsll((long long)bal) - 1;
  int exclv = __shfl(incl - own, srcl);
  int bstar = -1, below = 0, cum = exclv;
  for (int k = 0; k < 16; ++k) {
    int cnt = (int)hist[srcl * 16 + k];
    if (bstar < 0 && cum + cnt >= RANKC) { bstar = srcl * 16 + k; below = cum; }
    cum += cnt;
  }
  int kc = 0, ccn = 0;
#pragma unroll
  for (int t = 0; t < 36; ++t) {
    int j = t * 64 + lane;
    float r = rreg[t];
    int bin = (int)(__float_as_uint(r) >> 22);
    bool isk = bin < bstar, isc = bin == bstar;
    u64 bkm = __ballot(isk);
    u64 bcm = __ballot(isc);
    u64 mymask = (1ull << lane) - 1ull;
    if (isk) { int p = kc + __popcll(bkm & mymask); kidx[p] = j; kr[p] = r; }
    if (isc) { int p = ccn + __popcll(bcm & mymask); if (p < CANDCAP) { cidx[p] = j; cr[p] = r; } }
    kc += (int)__popcll(bkm);
    ccn += (int)__popcll(bcm);
  }
  __syncthreads();
  int m = RANKC - below;
  bool usec = (ccn <= CANDCAP);
  for (int s = 0; s < m; ++s) {
    float bvv = 3.402823466e38f; int bj = 0x7fffffff; int bp = -1;
    if (usec) {
      for (int p = lane; p < ccn; p += 64) {
        float v = cr[p]; int j = cidx[p];
        if (v < bvv || (v == bvv && j < bj)) { bvv = v; bj = j; bp = p; }
      }
    } else {
      for (int t = 0; t < 36; ++t) {
        int j = t * 64 + lane;
        float v = rcomp(j);
        if ((int)(__float_as_uint(v) >> 22) != bstar) continue;
        bool used = false;
        for (int u = 0; u < s; ++u) if (kidx[below + u] == j) { used = true; break; }
        if (!used && (v < bvv || (v == bvv && j < bj))) { bvv = v; bj = j; bp = -1; }
      }
    }
#pragma unroll
    for (int off = 32; off; off >>= 1) {
      float ov = __shfl_xor(bvv, off); int oj = __shfl_xor(bj, off); int op = __shfl_xor(bp, off);
      if (ov < bvv || (ov == bvv && oj < bj)) { bvv = ov; bj = oj; bp = op; }
    }
    if (lane == 0) {
      kidx[below + s] = bj; kr[below + s] = bvv;
      if (bp >= 0) cr[bp] = 3.402823466e38f;
    }
    __syncthreads();
  }
  if (lane == 0) {
    int ia = -1, ib = -1;
    for (int t = 0; t < RANKC; ++t) {
      bool gA = (ia < 0) || (kr[t] > kr[ia]) || (kr[t] == kr[ia] && kidx[t] > kidx[ia]);
      if (gA) { ib = ia; ia = t; }
      else {
        bool gB = (ib < 0) || (kr[t] > kr[ib]) || (kr[t] == kr[ib] && kidx[t] > kidx[ib]);
        if (gB) ib = t;
      }
    }
    float tau = 0.f;
    for (int u = 0; u < 2; ++u) {
      int t = u ? ib : ia;
      const float* kp = krb + (size_t)kidx[t] * 12;
      float sp = fabsf(dq.x * kp[0]) + fabsf(dq.y * kp[1]) + fabsf(dq.z * kp[2])
               + fabsf(kp[4] * mq.x) + fabsf(kp[5] * mq.y) + fabsf(kp[6] * mq.z);
      float den = (mq.w + kp[3]) + 1e-6f;
      tau += 20.0f * 5.9604645e-08f * sp / den + 4e-7f * kr[t];
    }
    s_alt = ia; s_last = ib;
    s_hedge = ((kr[ia] - kr[ib]) < tau) ? 1 : 0;
  }
  __syncthreads();
  // logits, transposed: 64 lanes cooperate per candidate (coalesced 1KB row read)
  for (int t = 0; t < RANKC; ++t) {
    int j = kidx[t];
    float4 k4 = *(const float4*)(kf + (size_t)(b * HW + j) * DD + lane * 4);
    float d = fmaf(k4.x, qreg.x, fmaf(k4.y, qreg.y, fmaf(k4.z, qreg.z, k4.w * qreg.w)));
#pragma unroll
    for (int off = 32; off; off >>= 1) d += __shfl_xor(d, off);
    if (lane == 0) lgt[t] = d * 0.0625f - kr[t] / 0.1f;
  }
  __syncthreads();
  // wave-parallel softmax (R15-verified pattern)
  int ia = s_alt, ib = s_last, hedge = s_hedge;
  {
    float lgt_l = (lane < RANKC) ? lgt[lane] : -3.402823466e38f;
    float mv = (lane < RANKC && lane != ia) ? lgt_l : -3.402823466e38f;
#pragma unroll
    for (int off = 32; off; off >>= 1) mv = fmaxf(mv, __shfl_xor(mv, off));
    float e1 = (lane < RANKC && lane != ia) ? expf(lgt_l - mv) : 0.f;
    float z1 = e1;
#pragma unroll
    for (int off = 32; off; off >>= 1) z1 += __shfl_xor(z1, off);
    float w1 = e1 / z1;
    if (lane < RANKC) wgt[lane] = w1;
    if (hedge) {
      float mv2 = (lane < RANKC && lane != ib) ? lgt_l : -3.402823466e38f;
#pragma unroll
      for (int off = 32; off; off >>= 1) mv2 = fmaxf(mv2, __shfl_xor(mv2, off));
      float e2 = (lane < RANKC && lane != ib) ? expf(lgt_l - mv2) : 0.f;
      float z2 = e2;
#pragma unroll
      for (int off = 32; off; off >>= 1) z2 += __shfl_xor(z2, off);
      if (lane < RANKC) dw[lane] = w1 - e2 / z2;
    }
  }
  __syncthreads();
  float4 o = make_float4(0.f, 0.f, 0.f, 0.f);
  float4 od = make_float4(0.f, 0.f, 0.f, 0.f);
  const float* vb = vf + (size_t)b * HW * DD;
  for (int tt = 0; tt < RANKC; ++tt) {
    float wv = wgt[tt]; int j = kidx[tt];
    float4 vv = *(const float4*)(vb + (size_t)j * DD + lane * 4);
    o.x = fmaf(wv, vv.x, o.x);
    o.y = fmaf(wv, vv.y, o.y);
    o.z = fmaf(wv, vv.z, o.z);
    o.w = fmaf(wv, vv.w, o.w);
    if (hedge) {
      float dv = dw[tt];
      od.x = fmaf(dv, vv.x, od.x);
      od.y = fmaf(dv, vv.y, od.y);
      od.z = fmaf(dv, vv.z, od.z);
      od.w = fmaf(dv, vv.w, od.w);
    }
  }
  *(float4*)(fusedf + (size_t)tok * DD + lane * 4) = o;
  if (hedge) *(float4*)(dfused + (size_t)tok * DD + lane * 4) = od;
  if (lane == 0) flags[tok] = hedge;
}

// ---------------- kernel 4b: hedge gate (UNCHANGED) ----------------
__global__ __launch_bounds__(256) void hedge_gate(
    const float* __restrict__ Wo, const int* __restrict__ flags,
    const float* __restrict__ dfused, float* __restrict__ fusedf) {
  int tok = blockIdx.x;
  if (!flags[tok]) return;
  __shared__ float dfl[DD];
  __shared__ float wmax[8];
  int tid = threadIdx.x;
  dfl[tid] = dfused[(size_t)tok * DD + tid];
  __syncthreads();
  float lmax = 0.f;
  for (int k = 0; k < 4; ++k) {
    int c = k * 256 + tid;
    const float* wr = Wo + (size_t)c * DD;
    float dot = 0.f;
#pragma unroll 8
    for (int d = 0; d < DD; d += 4) {
      float4 w4 = *(const float4*)(wr + d);
      float4 f4 = *(const float4*)(dfl + d);
      dot = fmaf(w4.x, f4.x, dot);
      dot = fmaf(w4.y, f4.y, dot);
      dot = fmaf(w4.z, f4.z, dot);
      dot = fmaf(w4.w, f4.w, dot);
    }
    lmax = fmaxf(lmax, fabsf(dot));
  }
#pragma unroll
  for (int off = 32; off; off >>= 1) lmax = fmaxf(lmax, __shfl_xor(lmax, off));
  if ((tid & 63) == 0) wmax[tid >> 6] = lmax;
  __syncthreads();
  if (tid == 0) wmax[4] = fmaxf(fmaxf(wmax[0], wmax[1]), fmaxf(wmax[2], wmax[3]));
  __syncthreads();
  if (wmax[4] <= GATE) {
    fusedf[(size_t)tok * DD + tid] -= 0.5f * dfl[tid];
  }
}

// ---------------- kernel 5: output projection, split-fp16 MFMA ----------------
__global__ __launch_bounds__(256) void out_mfma(
    const u16* __restrict__ woh, const u16* __restrict__ wol,
    const float* __restrict__ fusedf, const float* __restrict__ bo,
    float* __restrict__ out) {
  int itile = blockIdx.x, ctile = blockIdx.y, b = blockIdx.z;
  int i0 = itile * 128, c0 = ctile * 128;
  __shared__ u16 Bh[128 * 72], Bl[128 * 72];
  int tid = threadIdx.x, lane = tid & 63, wid = tid >> 6;
  int wm = (wid >> 1) * 64, wn = (wid & 1) * 64;
  f32x4 acc[4][4] = {};
  int rowA = lane & 15, kch = (lane >> 4) * 8;
  for (int ks = 0; ks < 4; ++ks) {
    int d0 = ks * 64;
#pragma unroll
    for (int p = 0; p < 4; ++p) {
      int rr = p * 32 + (tid >> 3);
      int dc = (tid & 7) * 8;
      const float* fp = &fusedf[(size_t)(b * HW + i0 + rr) * DD + d0 + dc];
      float4 f0 = *(const float4*)fp;
      float4 f1 = *(const float4*)(fp + 4);
      u16 h, l;
      split16(f0.x, h, l); Bh[rr * 72 + dc + 0] = h; Bl[rr * 72 + dc + 0] = l;
      split16(f0.y, h, l); Bh[rr * 72 + dc + 1] = h; Bl[rr * 72 + dc + 1] = l;
      split16(f0.z, h, l); Bh[rr * 72 + dc + 2] = h; Bl[rr * 72 + dc + 2] = l;
      split16(f0.w, h, l); Bh[rr * 72 + dc + 3] = h; Bl[rr * 72 + dc + 3] = l;
      split16(f1.x, h, l); Bh[rr * 72 + dc + 4] = h; Bl[rr * 72 + dc + 4] = l;
      split16(f1.y, h, l); Bh[rr * 72 + dc + 5] = h; Bl[rr * 72 + dc + 5] = l;
      split16(f1.z, h, l); Bh[rr * 72 + dc + 6] = h; Bl[rr * 72 + dc + 6] = l;
      split16(f1.w, h, l); Bh[rr * 72 + dc + 7] = h; Bl[rr * 72 + dc + 7] = l;
    }
    __syncthreads();
#pragma unroll
    for (int kk = 0; kk < 2; ++kk) {
      int ko = kk * 32 + kch;
      half8 ah[4], al[4], bh[4], bl[4];
#pragma unroll
      for (int mf = 0; mf < 4; ++mf) {
        size_t woff = (size_t)(c0 + wm + mf * 16 + rowA) * DD + d0 + ko;
        ah[mf] = *(const half8*)&woh[woff];
        al[mf] = *(const half8*)&wol[woff];
      }
#pragma unroll
      for (int nf = 0; nf < 4; ++nf) {
        bh[nf] = *(const half8*)&Bh[(wn + nf * 16 + rowA) * 72 + ko];
        bl[nf] = *(const half8*)&Bl[(wn + nf * 16 + rowA) * 72 + ko];
      }
#pragma unroll
      for (int mf = 0; mf < 4; ++mf)
#pragma unroll
        for (int nf = 0; nf < 4; ++nf) {
          acc[mf][nf] = __builtin_amdgcn_mfma_f32_16x16x32_f16(ah[mf], bh[nf], acc[mf][nf], 0, 0, 0);
          acc[mf][nf] = __builtin_amdgcn_mfma_f32_16x16x32_f16(ah[mf], bl[nf], acc[mf][nf], 0, 0, 0);
          acc[mf][nf] = __builtin_amdgcn_mfma_f32_16x16x32_f16(al[mf], bh[nf], acc[mf][nf], 0, 0, 0);
        }
    }
    __syncthreads();
  }
  int r4 = (lane >> 4) * 4, cold = lane & 15;
#pragma unroll
  for (int mf = 0; mf < 4; ++mf) {
#pragma unroll
    for (int r = 0; r < 4; ++r) {
      int crow = c0 + wm + mf * 16 + r4 + r;
      float bsv = bo[crow];
#pragma unroll
      for (int nf = 0; nf < 4; ++nf) {
        int icol = i0 + wn + nf * 16 + cold;
        out[(size_t)(b * CC + crow) * HW + icol] = acc[mf][nf][r] + bsv;
      }
    }
  }
}

extern "C" void kernel_launch(void* const* d_in, const int* in_sizes, int n_in,
                              void* d_out, int out_size, void* d_ws, size_t ws_size,
                              hipStream_t stream) {
  (void)in_sizes; (void)n_in; (void)out_size; (void)ws_size;
  const float* qmap = (const float*)d_in[0];
  const float* kvmap = (const float*)d_in[1];
  const float* pq = (const float*)d_in[2];
  const float* pk = (const float*)d_in[3];
  const float* lnqg = (const float*)d_in[4];
  const float* lnqb = (const float*)d_in[5];
  const float* lnkg = (const float*)d_in[6];
  const float* lnkb = (const float*)d_in[7];
  const float* Wq = (const float*)d_in[8];
  const float* bq = (const float*)d_in[9];
  const float* Wk = (const float*)d_in[10];
  const float* bk = (const float*)d_in[11];
  const float* Wv = (const float*)d_in[12];
  const float* bv = (const float*)d_in[13];
  const float* Wo = (const float*)d_in[14];
  const float* bo = (const float*)d_in[15];
  float* out = (float*)d_out;
  char* w = (char*)d_ws;
  size_t off = 0;
  auto take = [&](size_t n) { char* p = w + off; off += (n + 511) & ~(size_t)511; return p; };
  u16* wq_h = (u16*)take((size_t)DD * CC * 2);
  u16* wq_l = (u16*)take((size_t)DD * CC * 2);
  u16* wk_h = (u16*)take((size_t)DD * CC * 2);
  u16* wk_l = (u16*)take((size_t)DD * CC * 2);
  u16* wv_h = (u16*)take((size_t)DD * CC * 2);
  u16* wv_l = (u16*)take((size_t)DD * CC * 2);
  u16* wo_h = (u16*)take((size_t)CC * DD * 2);
  u16* wo_l = (u16*)take((size_t)CC * DD * 2);
  float* qray = (float*)take((size_t)NB * HW * 12 * 4);
  float* kray = (float*)take((size_t)NB * HW * 12 * 4);
  float* mu_q = (float*)take((size_t)NB * HW * 4);
  float* rs_q = (float*)take((size_t)NB * HW * 4);
  float* mu_k = (float*)take((size_t)NB * HW * 4);
  float* rs_k = (float*)take((size_t)NB * HW * 4);
  float* qf = (float*)take((size_t)NB * HW * DD * 4);
  float* kf = (float*)take((size_t)NB * HW * DD * 4);
  float* vf = (float*)take((size_t)NB * HW * DD * 4);
  float* fusedf = (float*)take((size_t)NB * HW * DD * 4);
  float* dfused = (float*)take((size_t)NB * HW * DD * 4);
  int* flags = (int*)take((size_t)NB * HW * 4);

  prep_weights<<<dim3(1024), 256, 0, stream>>>(Wq, Wk, Wv, Wo, wq_h, wq_l, wk_h, wk_l,
                                               wv_h, wv_l, wo_h, wo_l);
  prep_rays<<<dim3(36, 2), 256, 0, stream>>>(pq, pk, qray, kray);
  ln_stats<<<dim3(72, NB, 2), 256, 0, stream>>>(qmap, kvmap, mu_q, rs_q, mu_k, rs_k);
  proj_mfma<<<dim3(36, 3, NB), 256, 0, stream>>>(qmap, kvmap, lnqg, lnqb, lnkg, lnkb,
                                                 wq_h, wq_l, wk_h, wk_l, wv_h, wv_l,
                                                 bq, bk, bv, mu_q, rs_q, mu_k, rs_k,
                                                 qf, kf, vf);
  attn_f32<<<dim3(HW, NB), 64, 0, stream>>>(qf, kf, vf, qray, kray, fusedf, dfused, flags);
  hedge_gate<<<dim3(NB * HW), 256, 0, stream>>>(Wo, flags, dfused, fusedf);
  out_mfma<<<dim3(18, 8, NB), 256, 0, stream>>>(wo_h, wo_l, fusedf, bo, out);
}

// Round 19
// 361.137 us; speedup vs baseline: 1.0558x; 1.0558x over previous
//
#include <hip/hip_runtime.h>

typedef unsigned short u16;
typedef unsigned int u32;
typedef unsigned long long u64;
typedef _Float16 f16;
typedef __attribute__((ext_vector_type(8))) _Float16 half8;
typedef __attribute__((ext_vector_type(4))) float f32x4;

#define HW 2304
#define CC 1024
#define DD 256
#define NB 4
#define CANDCAP 256
#define RANKC 33
#define GATE 0.099f

// Strict IEEE f32 ops the compiler cannot contract into FMA (selection path only).
__device__ __forceinline__ float mul_s(float a, float b) {
  float r; asm("v_mul_f32 %0, %1, %2" : "=v"(r) : "v"(a), "v"(b)); return r;
}
__device__ __forceinline__ float add_s(float a, float b) {
  float r; asm("v_add_f32 %0, %1, %2" : "=v"(r) : "v"(a), "v"(b)); return r;
}
// 2-term fp16 split: x ≈ hi + lo, error ~2^-22 relative.
__device__ __forceinline__ void split16(float a, u16& hi, u16& lo) {
  f16 h = (f16)a;
  float hf = (float)h;
  f16 l = (f16)(a - hf);
  __builtin_memcpy(&hi, &h, 2);
  __builtin_memcpy(&lo, &l, 2);
}

// ---------------- kernel 0: weights -> fp16 hi/lo ----------------
__global__ void prep_weights(const float* __restrict__ wq, const float* __restrict__ wk,
                             const float* __restrict__ wv, const float* __restrict__ wo,
                             u16* __restrict__ qh, u16* __restrict__ ql,
                             u16* __restrict__ kh, u16* __restrict__ kl,
                             u16* __restrict__ vh, u16* __restrict__ vl,
                             u16* __restrict__ oh, u16* __restrict__ ol) {
  int idx = blockIdx.x * 256 + threadIdx.x;
  for (int i = idx; i < 4 * 262144; i += 262144) {
    int which = i >> 18, loc = i & 262143;
    const float* s = (which == 0) ? wq : (which == 1) ? wk : (which == 2) ? wv : wo;
    u16* dh = (which == 0) ? qh : (which == 1) ? kh : (which == 2) ? vh : oh;
    u16* dl = (which == 0) ? ql : (which == 1) ? kl : (which == 2) ? vl : ol;
    u16 h, l; split16(s[loc], h, l);
    dh[loc] = h; dl[loc] = l;
  }
}

// ---------------- kernel 1: ray preprocessing (strict IEEE, numpy-faithful) ----------------
__global__ void prep_rays(const float* __restrict__ pq, const float* __restrict__ pk,
                          float* __restrict__ qray, float* __restrict__ kray) {
#pragma clang fp contract(off)
  int t = blockIdx.x * 256 + threadIdx.x;
  const float* src = blockIdx.y ? pk : pq;
  float* dst = blockIdx.y ? kray : qray;
  int b = t / HW, i = t % HW;
  const float* sp = src + (size_t)b * 6 * HW + i;
  float d0 = sp[0], d1 = sp[HW], d2 = sp[2 * HW];
  float m0 = sp[3 * HW], m1 = sp[4 * HW], m2 = sp[5 * HW];
  float nd = __fsqrt_rn(add_s(add_s(mul_s(d0, d0), mul_s(d1, d1)), mul_s(d2, d2)));
  float nc = fmaxf(nd, 1e-6f);
  float ix = d0 / nc, iy = d1 / nc, iz = d2 / nc;
  float nm = __fsqrt_rn(add_s(add_s(mul_s(m0, m0), mul_s(m1, m1)), mul_s(m2, m2)));
  float4* dp = (float4*)(dst + (size_t)t * 12);
  dp[0] = make_float4(m0, m1, m2, nm);
  dp[1] = make_float4(ix, iy, iz, 0.f);
  dp[2] = make_float4(d0, d1, d2, 0.f);
}

// ---------------- kernel 2: LayerNorm stats ----------------
__global__ __launch_bounds__(256) void ln_stats(const float* __restrict__ qmap,
                                                const float* __restrict__ kvmap,
                                                float* __restrict__ mu_q, float* __restrict__ rs_q,
                                                float* __restrict__ mu_k, float* __restrict__ rs_k) {
  const float* src = blockIdx.z ? kvmap : qmap;
  float* mu = blockIdx.z ? mu_k : mu_q;
  float* rs = blockIdx.z ? rs_k : rs_q;
  int b = blockIdx.y;
  int i0 = blockIdx.x * 32;
  int lane = threadIdx.x & 31, strip = threadIdx.x >> 5;
  const float* p = src + (size_t)b * CC * HW + i0 + lane;
  float s = 0.f, s2 = 0.f;
  for (int c = strip; c < CC; c += 8) {
    float v = p[(size_t)c * HW];
    s += v; s2 += v * v;
  }
  __shared__ float rsum[8][32], rsq[8][32];
  rsum[strip][lane] = s; rsq[strip][lane] = s2;
  __syncthreads();
  if (threadIdx.x < 32) {
    float ts = 0.f, tq = 0.f;
    for (int k = 0; k < 8; ++k) { ts += rsum[k][lane]; tq += rsq[k][lane]; }
    float m = ts * (1.f / 1024.f);
    float var = fmaxf(tq * (1.f / 1024.f) - m * m, 0.f);
    mu[b * HW + i0 + lane] = m;
    rs[b * HW + i0 + lane] = rsqrtf(var + 1e-5f);
  }
}

// ---------------- kernel 3: LN + QKV projection, split-fp16 MFMA ----------------
__global__ __launch_bounds__(256) void proj_mfma(
    const float* __restrict__ qmap, const float* __restrict__ kvmap,
    const float* __restrict__ gq, const float* __restrict__ bgq,
    const float* __restrict__ gk, const float* __restrict__ bgk,
    const u16* __restrict__ wqh, const u16* __restrict__ wql,
    const u16* __restrict__ wkh, const u16* __restrict__ wkl,
    const u16* __restrict__ wvh, const u16* __restrict__ wvl,
    const float* __restrict__ bq, const float* __restrict__ bk, const float* __restrict__ bv,
    const float* __restrict__ muq, const float* __restrict__ rsq,
    const float* __restrict__ muk, const float* __restrict__ rsk,
    float* __restrict__ qf, float* __restrict__ kf, float* __restrict__ vf) {
  int mtile = blockIdx.x, proj = blockIdx.y, b = blockIdx.z;
  int i0 = mtile * 64;
  const float* A; const u16* Wh; const u16* Wl;
  const float* gamma; const float* beta; const float* mup; const float* rsp; const float* bias;
  float* outp;
  if (proj == 0)      { A = qmap;  Wh = wqh; Wl = wql; gamma = gq; beta = bgq; mup = muq; rsp = rsq; bias = bq; outp = qf; }
  else if (proj == 1) { A = kvmap; Wh = wkh; Wl = wkl; gamma = gk; beta = bgk; mup = muk; rsp = rsk; bias = bk; outp = kf; }
  else                { A = kvmap; Wh = wvh; Wl = wvl; gamma = nullptr; beta = nullptr; mup = nullptr; rsp = nullptr; bias = bv; outp = vf; }
  __shared__ u16 Ah[64 * 72], Al[64 * 72];
  __shared__ float mul[64], rsl[64];
  int tid = threadIdx.x;
  int lane = tid & 63, wid = tid >> 6;
  if (proj < 2 && tid < 64) {
    mul[tid] = mup[b * HW + i0 + tid];
    rsl[tid] = rsp[b * HW + i0 + tid];
  }
  __syncthreads();
  f32x4 acc[4][4] = {};
  int c_loc = tid >> 2;
  int i4 = (tid & 3) * 4;
  int rowA = lane & 15, kch = (lane >> 4) * 8;
  for (int ks = 0; ks < 16; ++ks) {
    int c0 = ks * 64;
    float gma = 1.f, bet = 0.f;
    if (proj < 2) { gma = gamma[c0 + c_loc]; bet = beta[c0 + c_loc]; }
    const float* ap = A + ((size_t)(b * CC + c0 + c_loc)) * HW + i0;
#pragma unroll
    for (int p = 0; p < 4; ++p) {
      int ib = p * 16 + i4;
      float4 v = *(const float4*)(ap + ib);
      float e0 = v.x, e1 = v.y, e2 = v.z, e3 = v.w;
      if (proj < 2) {
        e0 = (e0 - mul[ib + 0]) * rsl[ib + 0] * gma + bet;
        e1 = (e1 - mul[ib + 1]) * rsl[ib + 1] * gma + bet;
        e2 = (e2 - mul[ib + 2]) * rsl[ib + 2] * gma + bet;
        e3 = (e3 - mul[ib + 3]) * rsl[ib + 3] * gma + bet;
      }
      u16 h, l;
      split16(e0, h, l); Ah[(ib + 0) * 72 + c_loc] = h; Al[(ib + 0) * 72 + c_loc] = l;
      split16(e1, h, l); Ah[(ib + 1) * 72 + c_loc] = h; Al[(ib + 1) * 72 + c_loc] = l;
      split16(e2, h, l); Ah[(ib + 2) * 72 + c_loc] = h; Al[(ib + 2) * 72 + c_loc] = l;
      split16(e3, h, l); Ah[(ib + 3) * 72 + c_loc] = h; Al[(ib + 3) * 72 + c_loc] = l;
    }
    __syncthreads();
#pragma unroll
    for (int kk = 0; kk < 2; ++kk) {
      int ko = kk * 32 + kch;
      half8 ah[4], al[4], bh[4], bl[4];
#pragma unroll
      for (int mf = 0; mf < 4; ++mf) {
        ah[mf] = *(const half8*)&Ah[(mf * 16 + rowA) * 72 + ko];
        al[mf] = *(const half8*)&Al[(mf * 16 + rowA) * 72 + ko];
      }
#pragma unroll
      for (int nf = 0; nf < 4; ++nf) {
        size_t woff = (size_t)(wid * 64 + nf * 16 + rowA) * CC + c0 + ko;
        bh[nf] = *(const half8*)&Wh[woff];
        bl[nf] = *(const half8*)&Wl[woff];
      }
#pragma unroll
      for (int mf = 0; mf < 4; ++mf)
#pragma unroll
        for (int nf = 0; nf < 4; ++nf) {
          acc[mf][nf] = __builtin_amdgcn_mfma_f32_16x16x32_f16(ah[mf], bh[nf], acc[mf][nf], 0, 0, 0);
          acc[mf][nf] = __builtin_amdgcn_mfma_f32_16x16x32_f16(ah[mf], bl[nf], acc[mf][nf], 0, 0, 0);
          acc[mf][nf] = __builtin_amdgcn_mfma_f32_16x16x32_f16(al[mf], bh[nf], acc[mf][nf], 0, 0, 0);
        }
    }
    __syncthreads();
  }
  int r4 = (lane >> 4) * 4, cold = lane & 15;
#pragma unroll
  for (int nf = 0; nf < 4; ++nf) {
    int dcol = wid * 64 + nf * 16 + cold;
    float bsv = bias[dcol];
#pragma unroll
    for (int mf = 0; mf < 4; ++mf) {
#pragma unroll
      for (int r = 0; r < 4; ++r) {
        int irow = i0 + mf * 16 + r4 + r;
        outp[(size_t)(b * HW + irow) * DD + dcol] = acc[mf][nf][r] + bsv;
      }
    }
  }
}

// ---- kernel 4: top-33 + hedge attention, XCD swizzle + lane-PARALLEL logits (R16 form) ----
__global__ __launch_bounds__(64) void attn_f32(
    const float* __restrict__ qf, const float* __restrict__ kf, const float* __restrict__ vf,
    const float* __restrict__ qray, const float* __restrict__ kray,
    float* __restrict__ fusedf, float* __restrict__ dfused, int* __restrict__ flags) {
#pragma clang fp contract(off)
  // XCD-contiguous swizzle (bijective: 9216 % 8 == 0) — keeps each XCD's gather L2-hot.
  int flat = blockIdx.y * HW + blockIdx.x;
  int swz = (flat & 7) * ((NB * HW) / 8) + (flat >> 3);
  int b = swz / HW, i = swz - b * HW;
  int lane = threadIdx.x;
  __shared__ u32 hist[1024];
  __shared__ float qs[DD];
  __shared__ int kidx[RANKC];
  __shared__ float kr[RANKC];
  __shared__ float lgt[RANKC];
  __shared__ float wgt[RANKC];
  __shared__ float dw[RANKC];
  __shared__ int cidx[CANDCAP];
  __shared__ float cr[CANDCAP];
  __shared__ int s_alt, s_last, s_hedge;
  int tok = b * HW + i;
  ((float4*)qs)[lane] = ((const float4*)(qf + (size_t)tok * DD))[lane];
  const float* qp = qray + (size_t)tok * 12;
  float4 mq = ((const float4*)qp)[0];
  float4 dq = ((const float4*)qp)[1];
#pragma unroll
  for (int k = 0; k < 16; ++k) hist[lane * 16 + k] = 0;
  __syncthreads();
  const float* krb = kray + (size_t)b * HW * 12;
  auto rcomp = [&](int j) -> float {
    const float4* kp4 = (const float4*)(krb + (size_t)j * 12);
    float4 km = kp4[0], kd = kp4[1];
    float p0 = mul_s(dq.x, km.x), p1 = mul_s(dq.y, km.y), p2 = mul_s(dq.z, km.z);
    float s1 = add_s(add_s(p0, p2), p1);
    float q0 = mul_s(kd.x, mq.x), q1 = mul_s(kd.y, mq.y), q2 = mul_s(kd.z, mq.z);
    float s2 = add_s(add_s(q0, q2), q1);
    float num = fabsf(add_s(s1, s2));
    float den = add_s(add_s(mq.w, km.w), 1e-6f);
    return num / den;
  };
  float rreg[36];
#pragma unroll
  for (int t = 0; t < 36; ++t) {
    rreg[t] = rcomp(t * 64 + lane);
    atomicAdd(&hist[__float_as_uint(rreg[t]) >> 22], 1u);
  }
  __syncthreads();
  int own = 0;
#pragma unroll
  for (int k = 0; k < 16; ++k) own += (int)hist[lane * 16 + k];
  int incl = own;
  for (int off = 1; off < 64; off <<= 1) {
    int nn = __shfl_up(incl, off);
    if (lane >= off) incl += nn;
  }
  u64 bal = __ballot(incl >= RANKC);
  int srcl = __ffsll((long long)bal) - 1;
  int exclv = __shfl(incl - own, srcl);
  int bstar = -1, below = 0, cum = exclv;
  for (int k = 0; k < 16; ++k) {
    int cnt = (int)hist[srcl * 16 + k];
    if (bstar < 0 && cum + cnt >= RANKC) { bstar = srcl * 16 + k; below = cum; }
    cum += cnt;
  }
  int kc = 0, ccn = 0;
#pragma unroll
  for (int t = 0; t < 36; ++t) {
    int j = t * 64 + lane;
    float r = rreg[t];
    int bin = (int)(__float_as_uint(r) >> 22);
    bool isk = bin < bstar, isc = bin == bstar;
    u64 bkm = __ballot(isk);
    u64 bcm = __ballot(isc);
    u64 mymask = (1ull << lane) - 1ull;
    if (isk) { int p = kc + __popcll(bkm & mymask); kidx[p] = j; kr[p] = r; }
    if (isc) { int p = ccn + __popcll(bcm & mymask); if (p < CANDCAP) { cidx[p] = j; cr[p] = r; } }
    kc += (int)__popcll(bkm);
    ccn += (int)__popcll(bcm);
  }
  __syncthreads();
  int m = RANKC - below;
  bool usec = (ccn <= CANDCAP);
  for (int s = 0; s < m; ++s) {
    float bvv = 3.402823466e38f; int bj = 0x7fffffff; int bp = -1;
    if (usec) {
      for (int p = lane; p < ccn; p += 64) {
        float v = cr[p]; int j = cidx[p];
        if (v < bvv || (v == bvv && j < bj)) { bvv = v; bj = j; bp = p; }
      }
    } else {
      for (int t = 0; t < 36; ++t) {
        int j = t * 64 + lane;
        float v = rcomp(j);
        if ((int)(__float_as_uint(v) >> 22) != bstar) continue;
        bool used = false;
        for (int u = 0; u < s; ++u) if (kidx[below + u] == j) { used = true; break; }
        if (!used && (v < bvv || (v == bvv && j < bj))) { bvv = v; bj = j; bp = -1; }
      }
    }
#pragma unroll
    for (int off = 32; off; off >>= 1) {
      float ov = __shfl_xor(bvv, off); int oj = __shfl_xor(bj, off); int op = __shfl_xor(bp, off);
      if (ov < bvv || (ov == bvv && oj < bj)) { bvv = ov; bj = oj; bp = op; }
    }
    if (lane == 0) {
      kidx[below + s] = bj; kr[below + s] = bvv;
      if (bp >= 0) cr[bp] = 3.402823466e38f;
    }
    __syncthreads();
  }
  if (lane == 0) {
    int ia = -1, ib = -1;
    for (int t = 0; t < RANKC; ++t) {
      bool gA = (ia < 0) || (kr[t] > kr[ia]) || (kr[t] == kr[ia] && kidx[t] > kidx[ia]);
      if (gA) { ib = ia; ia = t; }
      else {
        bool gB = (ib < 0) || (kr[t] > kr[ib]) || (kr[t] == kr[ib] && kidx[t] > kidx[ib]);
        if (gB) ib = t;
      }
    }
    float tau = 0.f;
    for (int u = 0; u < 2; ++u) {
      int t = u ? ib : ia;
      const float* kp = krb + (size_t)kidx[t] * 12;
      float sp = fabsf(dq.x * kp[0]) + fabsf(dq.y * kp[1]) + fabsf(dq.z * kp[2])
               + fabsf(kp[4] * mq.x) + fabsf(kp[5] * mq.y) + fabsf(kp[6] * mq.z);
      float den = (mq.w + kp[3]) + 1e-6f;
      tau += 20.0f * 5.9604645e-08f * sp / den + 4e-7f * kr[t];
    }
    s_alt = ia; s_last = ib;
    s_hedge = ((kr[ia] - kr[ib]) < tau) ? 1 : 0;
  }
  __syncthreads();
  // logits: lane t owns candidate t — 33 independent parallel dot products (R16 form)
  if (lane < RANKC) {
    const float* kp = kf + (size_t)(b * HW + kidx[lane]) * DD;
    float dot = 0.f;
#pragma unroll 8
    for (int d2 = 0; d2 < DD / 4; ++d2) {
      float4 k4 = ((const float4*)kp)[d2];
      float4 q4 = ((const float4*)qs)[d2];
      dot = fmaf(k4.x, q4.x, dot);
      dot = fmaf(k4.y, q4.y, dot);
      dot = fmaf(k4.z, q4.z, dot);
      dot = fmaf(k4.w, q4.w, dot);
    }
    lgt[lane] = dot * 0.0625f - kr[lane] / 0.1f;
  }
  __syncthreads();
  // wave-parallel softmax
  int ia = s_alt, ib = s_last, hedge = s_hedge;
  {
    float lgt_l = (lane < RANKC) ? lgt[lane] : -3.402823466e38f;
    float mv = (lane < RANKC && lane != ia) ? lgt_l : -3.402823466e38f;
#pragma unroll
    for (int off = 32; off; off >>= 1) mv = fmaxf(mv, __shfl_xor(mv, off));
    float e1 = (lane < RANKC && lane != ia) ? expf(lgt_l - mv) : 0.f;
    float z1 = e1;
#pragma unroll
    for (int off = 32; off; off >>= 1) z1 += __shfl_xor(z1, off);
    float w1 = e1 / z1;
    if (lane < RANKC) wgt[lane] = w1;
    if (hedge) {
      float mv2 = (lane < RANKC && lane != ib) ? lgt_l : -3.402823466e38f;
#pragma unroll
      for (int off = 32; off; off >>= 1) mv2 = fmaxf(mv2, __shfl_xor(mv2, off));
      float e2 = (lane < RANKC && lane != ib) ? expf(lgt_l - mv2) : 0.f;
      float z2 = e2;
#pragma unroll
      for (int off = 32; off; off >>= 1) z2 += __shfl_xor(z2, off);
      if (lane < RANKC) dw[lane] = w1 - e2 / z2;
    }
  }
  __syncthreads();
  float4 o = make_float4(0.f, 0.f, 0.f, 0.f);
  float4 od = make_float4(0.f, 0.f, 0.f, 0.f);
  const float* vb = vf + (size_t)b * HW * DD;
  for (int tt = 0; tt < RANKC; ++tt) {
    float wv = wgt[tt]; int j = kidx[tt];
    float4 vv = *(const float4*)(vb + (size_t)j * DD + lane * 4);
    o.x = fmaf(wv, vv.x, o.x);
    o.y = fmaf(wv, vv.y, o.y);
    o.z = fmaf(wv, vv.z, o.z);
    o.w = fmaf(wv, vv.w, o.w);
    if (hedge) {
      float dv = dw[tt];
      od.x = fmaf(dv, vv.x, od.x);
      od.y = fmaf(dv, vv.y, od.y);
      od.z = fmaf(dv, vv.z, od.z);
      od.w = fmaf(dv, vv.w, od.w);
    }
  }
  *(float4*)(fusedf + (size_t)tok * DD + lane * 4) = o;
  if (hedge) *(float4*)(dfused + (size_t)tok * DD + lane * 4) = od;
  if (lane == 0) flags[tok] = hedge;
}

// ---------------- kernel 4b: hedge gate (UNCHANGED) ----------------
__global__ __launch_bounds__(256) void hedge_gate(
    const float* __restrict__ Wo, const int* __restrict__ flags,
    const float* __restrict__ dfused, float* __restrict__ fusedf) {
  int tok = blockIdx.x;
  if (!flags[tok]) return;
  __shared__ float dfl[DD];
  __shared__ float wmax[8];
  int tid = threadIdx.x;
  dfl[tid] = dfused[(size_t)tok * DD + tid];
  __syncthreads();
  float lmax = 0.f;
  for (int k = 0; k < 4; ++k) {
    int c = k * 256 + tid;
    const float* wr = Wo + (size_t)c * DD;
    float dot = 0.f;
#pragma unroll 8
    for (int d = 0; d < DD; d += 4) {
      float4 w4 = *(const float4*)(wr + d);
      float4 f4 = *(const float4*)(dfl + d);
      dot = fmaf(w4.x, f4.x, dot);
      dot = fmaf(w4.y, f4.y, dot);
      dot = fmaf(w4.z, f4.z, dot);
      dot = fmaf(w4.w, f4.w, dot);
    }
    lmax = fmaxf(lmax, fabsf(dot));
  }
#pragma unroll
  for (int off = 32; off; off >>= 1) lmax = fmaxf(lmax, __shfl_xor(lmax, off));
  if ((tid & 63) == 0) wmax[tid >> 6] = lmax;
  __syncthreads();
  if (tid == 0) wmax[4] = fmaxf(fmaxf(wmax[0], wmax[1]), fmaxf(wmax[2], wmax[3]));
  __syncthreads();
  if (wmax[4] <= GATE) {
    fusedf[(size_t)tok * DD + tid] -= 0.5f * dfl[tid];
  }
}

// ---------------- kernel 5: output projection, split-fp16 MFMA ----------------
__global__ __launch_bounds__(256) void out_mfma(
    const u16* __restrict__ woh, const u16* __restrict__ wol,
    const float* __restrict__ fusedf, const float* __restrict__ bo,
    float* __restrict__ out) {
  int itile = blockIdx.x, ctile = blockIdx.y, b = blockIdx.z;
  int i0 = itile * 128, c0 = ctile * 128;
  __shared__ u16 Bh[128 * 72], Bl[128 * 72];
  int tid = threadIdx.x, lane = tid & 63, wid = tid >> 6;
  int wm = (wid >> 1) * 64, wn = (wid & 1) * 64;
  f32x4 acc[4][4] = {};
  int rowA = lane & 15, kch = (lane >> 4) * 8;
  for (int ks = 0; ks < 4; ++ks) {
    int d0 = ks * 64;
#pragma unroll
    for (int p = 0; p < 4; ++p) {
      int rr = p * 32 + (tid >> 3);
      int dc = (tid & 7) * 8;
      const float* fp = &fusedf[(size_t)(b * HW + i0 + rr) * DD + d0 + dc];
      float4 f0 = *(const float4*)fp;
      float4 f1 = *(const float4*)(fp + 4);
      u16 h, l;
      split16(f0.x, h, l); Bh[rr * 72 + dc + 0] = h; Bl[rr * 72 + dc + 0] = l;
      split16(f0.y, h, l); Bh[rr * 72 + dc + 1] = h; Bl[rr * 72 + dc + 1] = l;
      split16(f0.z, h, l); Bh[rr * 72 + dc + 2] = h; Bl[rr * 72 + dc + 2] = l;
      split16(f0.w, h, l); Bh[rr * 72 + dc + 3] = h; Bl[rr * 72 + dc + 3] = l;
      split16(f1.x, h, l); Bh[rr * 72 + dc + 4] = h; Bl[rr * 72 + dc + 4] = l;
      split16(f1.y, h, l); Bh[rr * 72 + dc + 5] = h; Bl[rr * 72 + dc + 5] = l;
      split16(f1.z, h, l); Bh[rr * 72 + dc + 6] = h; Bl[rr * 72 + dc + 6] = l;
      split16(f1.w, h, l); Bh[rr * 72 + dc + 7] = h; Bl[rr * 72 + dc + 7] = l;
    }
    __syncthreads();
#pragma unroll
    for (int kk = 0; kk < 2; ++kk) {
      int ko = kk * 32 + kch;
      half8 ah[4], al[4], bh[4], bl[4];
#pragma unroll
      for (int mf = 0; mf < 4; ++mf) {
        size_t woff = (size_t)(c0 + wm + mf * 16 + rowA) * DD + d0 + ko;
        ah[mf] = *(const half8*)&woh[woff];
        al[mf] = *(const half8*)&wol[woff];
      }
#pragma unroll
      for (int nf = 0; nf < 4; ++nf) {
        bh[nf] = *(const half8*)&Bh[(wn + nf * 16 + rowA) * 72 + ko];
        bl[nf] = *(const half8*)&Bl[(wn + nf * 16 + rowA) * 72 + ko];
      }
#pragma unroll
      for (int mf = 0; mf < 4; ++mf)
#pragma unroll
        for (int nf = 0; nf < 4; ++nf) {
          acc[mf][nf] = __builtin_amdgcn_mfma_f32_16x16x32_f16(ah[mf], bh[nf], acc[mf][nf], 0, 0, 0);
          acc[mf][nf] = __builtin_amdgcn_mfma_f32_16x16x32_f16(ah[mf], bl[nf], acc[mf][nf], 0, 0, 0);
          acc[mf][nf] = __builtin_amdgcn_mfma_f32_16x16x32_f16(al[mf], bh[nf], acc[mf][nf], 0, 0, 0);
        }
    }
    __syncthreads();
  }
  int r4 = (lane >> 4) * 4, cold = lane & 15;
#pragma unroll
  for (int mf = 0; mf < 4; ++mf) {
#pragma unroll
    for (int r = 0; r < 4; ++r) {
      int crow = c0 + wm + mf * 16 + r4 + r;
      float bsv = bo[crow];
#pragma unroll
      for (int nf = 0; nf < 4; ++nf) {
        int icol = i0 + wn + nf * 16 + cold;
        out[(size_t)(b * CC + crow) * HW + icol] = acc[mf][nf][r] + bsv;
      }
    }
  }
}

extern "C" void kernel_launch(void* const* d_in, const int* in_sizes, int n_in,
                              void* d_out, int out_size, void* d_ws, size_t ws_size,
                              hipStream_t stream) {
  (void)in_sizes; (void)n_in; (void)out_size; (void)ws_size;
  const float* qmap = (const float*)d_in[0];
  const float* kvmap = (const float*)d_in[1];
  const float* pq = (const float*)d_in[2];
  const float* pk = (const float*)d_in[3];
  const float* lnqg = (const float*)d_in[4];
  const float* lnqb = (const float*)d_in[5];
  const float* lnkg = (const float*)d_in[6];
  const float* lnkb = (const float*)d_in[7];
  const float* Wq = (const float*)d_in[8];
  const float* bq = (const float*)d_in[9];
  const float* Wk = (const float*)d_in[10];
  const float* bk = (const float*)d_in[11];
  const float* Wv = (const float*)d_in[12];
  const float* bv = (const float*)d_in[13];
  const float* Wo = (const float*)d_in[14];
  const float* bo = (const float*)d_in[15];
  float* out = (float*)d_out;
  char* w = (char*)d_ws;
  size_t off = 0;
  auto take = [&](size_t n) { char* p = w + off; off += (n + 511) & ~(size_t)511; return p; };
  u16* wq_h = (u16*)take((size_t)DD * CC * 2);
  u16* wq_l = (u16*)take((size_t)DD * CC * 2);
  u16* wk_h = (u16*)take((size_t)DD * CC * 2);
  u16* wk_l = (u16*)take((size_t)DD * CC * 2);
  u16* wv_h = (u16*)take((size_t)DD * CC * 2);
  u16* wv_l = (u16*)take((size_t)DD * CC * 2);
  u16* wo_h = (u16*)take((size_t)CC * DD * 2);
  u16* wo_l = (u16*)take((size_t)CC * DD * 2);
  float* qray = (float*)take((size_t)NB * HW * 12 * 4);
  float* kray = (float*)take((size_t)NB * HW * 12 * 4);
  float* mu_q = (float*)take((size_t)NB * HW * 4);
  float* rs_q = (float*)take((size_t)NB * HW * 4);
  float* mu_k = (float*)take((size_t)NB * HW * 4);
  float* rs_k = (float*)take((size_t)NB * HW * 4);
  float* qf = (float*)take((size_t)NB * HW * DD * 4);
  float* kf = (float*)take((size_t)NB * HW * DD * 4);
  float* vf = (float*)take((size_t)NB * HW * DD * 4);
  float* fusedf = (float*)take((size_t)NB * HW * DD * 4);
  float* dfused = (float*)take((size_t)NB * HW * DD * 4);
  int* flags = (int*)take((size_t)NB * HW * 4);

  prep_weights<<<dim3(1024), 256, 0, stream>>>(Wq, Wk, Wv, Wo, wq_h, wq_l, wk_h, wk_l,
                                               wv_h, wv_l, wo_h, wo_l);
  prep_rays<<<dim3(36, 2), 256, 0, stream>>>(pq, pk, qray, kray);
  ln_stats<<<dim3(72, NB, 2), 256, 0, stream>>>(qmap, kvmap, mu_q, rs_q, mu_k, rs_k);
  proj_mfma<<<dim3(36, 3, NB), 256, 0, stream>>>(qmap, kvmap, lnqg, lnqb, lnkg, lnkb,
                                                 wq_h, wq_l, wk_h, wk_l, wv_h, wv_l,
                                                 bq, bk, bv, mu_q, rs_q, mu_k, rs_k,
                                                 qf, kf, vf);
  attn_f32<<<dim3(HW, NB), 64, 0, stream>>>(qf, kf, vf, qray, kray, fusedf, dfused, flags);
  hedge_gate<<<dim3(NB * HW), 256, 0, stream>>>(Wo, flags, dfused, fusedf);
  out_mfma<<<dim3(18, 8, NB), 256, 0, stream>>>(wo_h, wo_l, fusedf, bo, out);
}

// Round 20
// 311.379 us; speedup vs baseline: 1.2245x; 1.1598x over previous
//
#include <hip/hip_runtime.h>

typedef unsigned short u16;
typedef unsigned int u32;
typedef unsigned long long u64;
typedef _Float16 f16;
typedef __attribute__((ext_vector_type(8))) _Float16 half8;
typedef __attribute__((ext_vector_type(4))) float f32x4;

#define HW 2304
#define CC 1024
#define DD 256
#define NB 4
#define CANDCAP 256
#define RANKC 33
#define GATE 0.099f
#define MAXH 512

// Strict IEEE f32 ops the compiler cannot contract into FMA (selection path only).
__device__ __forceinline__ float mul_s(float a, float b) {
  float r; asm("v_mul_f32 %0, %1, %2" : "=v"(r) : "v"(a), "v"(b)); return r;
}
__device__ __forceinline__ float add_s(float a, float b) {
  float r; asm("v_add_f32 %0, %1, %2" : "=v"(r) : "v"(a), "v"(b)); return r;
}
// 2-term fp16 split: x ≈ hi + lo, error ~2^-22 relative.
__device__ __forceinline__ void split16(float a, u16& hi, u16& lo) {
  f16 h = (f16)a;
  float hf = (float)h;
  f16 l = (f16)(a - hf);
  __builtin_memcpy(&hi, &h, 2);
  __builtin_memcpy(&lo, &l, 2);
}

// ---------------- kernel 0: weights -> fp16 hi/lo ----------------
__global__ void prep_weights(const float* __restrict__ wq, const float* __restrict__ wk,
                             const float* __restrict__ wv, const float* __restrict__ wo,
                             u16* __restrict__ qh, u16* __restrict__ ql,
                             u16* __restrict__ kh, u16* __restrict__ kl,
                             u16* __restrict__ vh, u16* __restrict__ vl,
                             u16* __restrict__ oh, u16* __restrict__ ol) {
  int idx = blockIdx.x * 256 + threadIdx.x;
  for (int i = idx; i < 4 * 262144; i += 262144) {
    int which = i >> 18, loc = i & 262143;
    const float* s = (which == 0) ? wq : (which == 1) ? wk : (which == 2) ? wv : wo;
    u16* dh = (which == 0) ? qh : (which == 1) ? kh : (which == 2) ? vh : oh;
    u16* dl = (which == 0) ? ql : (which == 1) ? kl : (which == 2) ? vl : ol;
    u16 h, l; split16(s[loc], h, l);
    dh[loc] = h; dl[loc] = l;
  }
}

// ---------------- kernel 1: ray preprocessing (strict IEEE, numpy-faithful) ----------------
__global__ void prep_rays(const float* __restrict__ pq, const float* __restrict__ pk,
                          float* __restrict__ qray, float* __restrict__ kray) {
#pragma clang fp contract(off)
  int t = blockIdx.x * 256 + threadIdx.x;
  const float* src = blockIdx.y ? pk : pq;
  float* dst = blockIdx.y ? kray : qray;
  int b = t / HW, i = t % HW;
  const float* sp = src + (size_t)b * 6 * HW + i;
  float d0 = sp[0], d1 = sp[HW], d2 = sp[2 * HW];
  float m0 = sp[3 * HW], m1 = sp[4 * HW], m2 = sp[5 * HW];
  float nd = __fsqrt_rn(add_s(add_s(mul_s(d0, d0), mul_s(d1, d1)), mul_s(d2, d2)));
  float nc = fmaxf(nd, 1e-6f);
  float ix = d0 / nc, iy = d1 / nc, iz = d2 / nc;
  float nm = __fsqrt_rn(add_s(add_s(mul_s(m0, m0), mul_s(m1, m1)), mul_s(m2, m2)));
  float4* dp = (float4*)(dst + (size_t)t * 12);
  dp[0] = make_float4(m0, m1, m2, nm);
  dp[1] = make_float4(ix, iy, iz, 0.f);
  dp[2] = make_float4(d0, d1, d2, 0.f);
}

// ---------------- kernel 2: LayerNorm stats ----------------
__global__ __launch_bounds__(256) void ln_stats(const float* __restrict__ qmap,
                                                const float* __restrict__ kvmap,
                                                float* __restrict__ mu_q, float* __restrict__ rs_q,
                                                float* __restrict__ mu_k, float* __restrict__ rs_k) {
  const float* src = blockIdx.z ? kvmap : qmap;
  float* mu = blockIdx.z ? mu_k : mu_q;
  float* rs = blockIdx.z ? rs_k : rs_q;
  int b = blockIdx.y;
  int i0 = blockIdx.x * 32;
  int lane = threadIdx.x & 31, strip = threadIdx.x >> 5;
  const float* p = src + (size_t)b * CC * HW + i0 + lane;
  float s = 0.f, s2 = 0.f;
  for (int c = strip; c < CC; c += 8) {
    float v = p[(size_t)c * HW];
    s += v; s2 += v * v;
  }
  __shared__ float rsum[8][32], rsq[8][32];
  rsum[strip][lane] = s; rsq[strip][lane] = s2;
  __syncthreads();
  if (threadIdx.x < 32) {
    float ts = 0.f, tq = 0.f;
    for (int k = 0; k < 8; ++k) { ts += rsum[k][lane]; tq += rsq[k][lane]; }
    float m = ts * (1.f / 1024.f);
    float var = fmaxf(tq * (1.f / 1024.f) - m * m, 0.f);
    mu[b * HW + i0 + lane] = m;
    rs[b * HW + i0 + lane] = rsqrtf(var + 1e-5f);
  }
}

// ---------------- kernel 3: LN + QKV projection, split-fp16 MFMA ----------------
__global__ __launch_bounds__(256) void proj_mfma(
    const float* __restrict__ qmap, const float* __restrict__ kvmap,
    const float* __restrict__ gq, const float* __restrict__ bgq,
    const float* __restrict__ gk, const float* __restrict__ bgk,
    const u16* __restrict__ wqh, const u16* __restrict__ wql,
    const u16* __restrict__ wkh, const u16* __restrict__ wkl,
    const u16* __restrict__ wvh, const u16* __restrict__ wvl,
    const float* __restrict__ bq, const float* __restrict__ bk, const float* __restrict__ bv,
    const float* __restrict__ muq, const float* __restrict__ rsq,
    const float* __restrict__ muk, const float* __restrict__ rsk,
    float* __restrict__ qf, float* __restrict__ kf, float* __restrict__ vf) {
  int mtile = blockIdx.x, proj = blockIdx.y, b = blockIdx.z;
  int i0 = mtile * 64;
  const float* A; const u16* Wh; const u16* Wl;
  const float* gamma; const float* beta; const float* mup; const float* rsp; const float* bias;
  float* outp;
  if (proj == 0)      { A = qmap;  Wh = wqh; Wl = wql; gamma = gq; beta = bgq; mup = muq; rsp = rsq; bias = bq; outp = qf; }
  else if (proj == 1) { A = kvmap; Wh = wkh; Wl = wkl; gamma = gk; beta = bgk; mup = muk; rsp = rsk; bias = bk; outp = kf; }
  else                { A = kvmap; Wh = wvh; Wl = wvl; gamma = nullptr; beta = nullptr; mup = nullptr; rsp = nullptr; bias = bv; outp = vf; }
  __shared__ u16 Ah[64 * 72], Al[64 * 72];
  __shared__ float mul[64], rsl[64];
  int tid = threadIdx.x;
  int lane = tid & 63, wid = tid >> 6;
  if (proj < 2 && tid < 64) {
    mul[tid] = mup[b * HW + i0 + tid];
    rsl[tid] = rsp[b * HW + i0 + tid];
  }
  __syncthreads();
  f32x4 acc[4][4] = {};
  int c_loc = tid >> 2;
  int i4 = (tid & 3) * 4;
  int rowA = lane & 15, kch = (lane >> 4) * 8;
  for (int ks = 0; ks < 16; ++ks) {
    int c0 = ks * 64;
    float gma = 1.f, bet = 0.f;
    if (proj < 2) { gma = gamma[c0 + c_loc]; bet = beta[c0 + c_loc]; }
    const float* ap = A + ((size_t)(b * CC + c0 + c_loc)) * HW + i0;
#pragma unroll
    for (int p = 0; p < 4; ++p) {
      int ib = p * 16 + i4;
      float4 v = *(const float4*)(ap + ib);
      float e0 = v.x, e1 = v.y, e2 = v.z, e3 = v.w;
      if (proj < 2) {
        e0 = (e0 - mul[ib + 0]) * rsl[ib + 0] * gma + bet;
        e1 = (e1 - mul[ib + 1]) * rsl[ib + 1] * gma + bet;
        e2 = (e2 - mul[ib + 2]) * rsl[ib + 2] * gma + bet;
        e3 = (e3 - mul[ib + 3]) * rsl[ib + 3] * gma + bet;
      }
      u16 h, l;
      split16(e0, h, l); Ah[(ib + 0) * 72 + c_loc] = h; Al[(ib + 0) * 72 + c_loc] = l;
      split16(e1, h, l); Ah[(ib + 1) * 72 + c_loc] = h; Al[(ib + 1) * 72 + c_loc] = l;
      split16(e2, h, l); Ah[(ib + 2) * 72 + c_loc] = h; Al[(ib + 2) * 72 + c_loc] = l;
      split16(e3, h, l); Ah[(ib + 3) * 72 + c_loc] = h; Al[(ib + 3) * 72 + c_loc] = l;
    }
    __syncthreads();
#pragma unroll
    for (int kk = 0; kk < 2; ++kk) {
      int ko = kk * 32 + kch;
      half8 ah[4], al[4], bh[4], bl[4];
#pragma unroll
      for (int mf = 0; mf < 4; ++mf) {
        ah[mf] = *(const half8*)&Ah[(mf * 16 + rowA) * 72 + ko];
        al[mf] = *(const half8*)&Al[(mf * 16 + rowA) * 72 + ko];
      }
#pragma unroll
      for (int nf = 0; nf < 4; ++nf) {
        size_t woff = (size_t)(wid * 64 + nf * 16 + rowA) * CC + c0 + ko;
        bh[nf] = *(const half8*)&Wh[woff];
        bl[nf] = *(const half8*)&Wl[woff];
      }
#pragma unroll
      for (int mf = 0; mf < 4; ++mf)
#pragma unroll
        for (int nf = 0; nf < 4; ++nf) {
          acc[mf][nf] = __builtin_amdgcn_mfma_f32_16x16x32_f16(ah[mf], bh[nf], acc[mf][nf], 0, 0, 0);
          acc[mf][nf] = __builtin_amdgcn_mfma_f32_16x16x32_f16(ah[mf], bl[nf], acc[mf][nf], 0, 0, 0);
          acc[mf][nf] = __builtin_amdgcn_mfma_f32_16x16x32_f16(al[mf], bh[nf], acc[mf][nf], 0, 0, 0);
        }
    }
    __syncthreads();
  }
  int r4 = (lane >> 4) * 4, cold = lane & 15;
#pragma unroll
  for (int nf = 0; nf < 4; ++nf) {
    int dcol = wid * 64 + nf * 16 + cold;
    float bsv = bias[dcol];
#pragma unroll
    for (int mf = 0; mf < 4; ++mf) {
#pragma unroll
      for (int r = 0; r < 4; ++r) {
        int irow = i0 + mf * 16 + r4 + r;
        outp[(size_t)(b * HW + irow) * DD + dcol] = acc[mf][nf][r] + bsv;
      }
    }
  }
}

// ---------------- kernel H0: zero hedge counter + gmax ----------------
__global__ void hedge_init(int* __restrict__ hcount, u32* __restrict__ gmax) {
  int t = blockIdx.x * 256 + threadIdx.x;
  if (t == 0) *hcount = 0;
  if (t < MAXH) gmax[t] = 0;
}

// ---- kernel 4: top-33 + hedge attention, XCD swizzle + lane-parallel logits ----
__global__ __launch_bounds__(64) void attn_f32(
    const float* __restrict__ qf, const float* __restrict__ kf, const float* __restrict__ vf,
    const float* __restrict__ qray, const float* __restrict__ kray,
    float* __restrict__ fusedf, float* __restrict__ dfused,
    int* __restrict__ hcount, int* __restrict__ hlist) {
#pragma clang fp contract(off)
  int flat = blockIdx.y * HW + blockIdx.x;
  int swz = (flat & 7) * ((NB * HW) / 8) + (flat >> 3);
  int b = swz / HW, i = swz - b * HW;
  int lane = threadIdx.x;
  __shared__ u32 hist[1024];
  __shared__ float qs[DD];
  __shared__ int kidx[RANKC];
  __shared__ float kr[RANKC];
  __shared__ float lgt[RANKC];
  __shared__ float wgt[RANKC];
  __shared__ float dw[RANKC];
  __shared__ int cidx[CANDCAP];
  __shared__ float cr[CANDCAP];
  __shared__ int s_alt, s_last, s_hedge;
  int tok = b * HW + i;
  ((float4*)qs)[lane] = ((const float4*)(qf + (size_t)tok * DD))[lane];
  const float* qp = qray + (size_t)tok * 12;
  float4 mq = ((const float4*)qp)[0];
  float4 dq = ((const float4*)qp)[1];
#pragma unroll
  for (int k = 0; k < 16; ++k) hist[lane * 16 + k] = 0;
  __syncthreads();
  const float* krb = kray + (size_t)b * HW * 12;
  auto rcomp = [&](int j) -> float {
    const float4* kp4 = (const float4*)(krb + (size_t)j * 12);
    float4 km = kp4[0], kd = kp4[1];
    float p0 = mul_s(dq.x, km.x), p1 = mul_s(dq.y, km.y), p2 = mul_s(dq.z, km.z);
    float s1 = add_s(add_s(p0, p2), p1);
    float q0 = mul_s(kd.x, mq.x), q1 = mul_s(kd.y, mq.y), q2 = mul_s(kd.z, mq.z);
    float s2 = add_s(add_s(q0, q2), q1);
    float num = fabsf(add_s(s1, s2));
    float den = add_s(add_s(mq.w, km.w), 1e-6f);
    return num / den;
  };
  float rreg[36];
#pragma unroll
  for (int t = 0; t < 36; ++t) {
    rreg[t] = rcomp(t * 64 + lane);
    atomicAdd(&hist[__float_as_uint(rreg[t]) >> 22], 1u);
  }
  __syncthreads();
  int own = 0;
#pragma unroll
  for (int k = 0; k < 16; ++k) own += (int)hist[lane * 16 + k];
  int incl = own;
  for (int off = 1; off < 64; off <<= 1) {
    int nn = __shfl_up(incl, off);
    if (lane >= off) incl += nn;
  }
  u64 bal = __ballot(incl >= RANKC);
  int srcl = __ffsll((long long)bal) - 1;
  int exclv = __shfl(incl - own, srcl);
  int bstar = -1, below = 0, cum = exclv;
  for (int k = 0; k < 16; ++k) {
    int cnt = (int)hist[srcl * 16 + k];
    if (bstar < 0 && cum + cnt >= RANKC) { bstar = srcl * 16 + k; below = cum; }
    cum += cnt;
  }
  int kc = 0, ccn = 0;
#pragma unroll
  for (int t = 0; t < 36; ++t) {
    int j = t * 64 + lane;
    float r = rreg[t];
    int bin = (int)(__float_as_uint(r) >> 22);
    bool isk = bin < bstar, isc = bin == bstar;
    u64 bkm = __ballot(isk);
    u64 bcm = __ballot(isc);
    u64 mymask = (1ull << lane) - 1ull;
    if (isk) { int p = kc + __popcll(bkm & mymask); kidx[p] = j; kr[p] = r; }
    if (isc) { int p = ccn + __popcll(bcm & mymask); if (p < CANDCAP) { cidx[p] = j; cr[p] = r; } }
    kc += (int)__popcll(bkm);
    ccn += (int)__popcll(bcm);
  }
  __syncthreads();
  int m = RANKC - below;
  bool usec = (ccn <= CANDCAP);
  for (int s = 0; s < m; ++s) {
    float bvv = 3.402823466e38f; int bj = 0x7fffffff; int bp = -1;
    if (usec) {
      for (int p = lane; p < ccn; p += 64) {
        float v = cr[p]; int j = cidx[p];
        if (v < bvv || (v == bvv && j < bj)) { bvv = v; bj = j; bp = p; }
      }
    } else {
      for (int t = 0; t < 36; ++t) {
        int j = t * 64 + lane;
        float v = rcomp(j);
        if ((int)(__float_as_uint(v) >> 22) != bstar) continue;
        bool used = false;
        for (int u = 0; u < s; ++u) if (kidx[below + u] == j) { used = true; break; }
        if (!used && (v < bvv || (v == bvv && j < bj))) { bvv = v; bj = j; bp = -1; }
      }
    }
#pragma unroll
    for (int off = 32; off; off >>= 1) {
      float ov = __shfl_xor(bvv, off); int oj = __shfl_xor(bj, off); int op = __shfl_xor(bp, off);
      if (ov < bvv || (ov == bvv && oj < bj)) { bvv = ov; bj = oj; bp = op; }
    }
    if (lane == 0) {
      kidx[below + s] = bj; kr[below + s] = bvv;
      if (bp >= 0) cr[bp] = 3.402823466e38f;
    }
    __syncthreads();
  }
  if (lane == 0) {
    int ia = -1, ib = -1;
    for (int t = 0; t < RANKC; ++t) {
      bool gA = (ia < 0) || (kr[t] > kr[ia]) || (kr[t] == kr[ia] && kidx[t] > kidx[ia]);
      if (gA) { ib = ia; ia = t; }
      else {
        bool gB = (ib < 0) || (kr[t] > kr[ib]) || (kr[t] == kr[ib] && kidx[t] > kidx[ib]);
        if (gB) ib = t;
      }
    }
    float tau = 0.f;
    for (int u = 0; u < 2; ++u) {
      int t = u ? ib : ia;
      const float* kp = krb + (size_t)kidx[t] * 12;
      float sp = fabsf(dq.x * kp[0]) + fabsf(dq.y * kp[1]) + fabsf(dq.z * kp[2])
               + fabsf(kp[4] * mq.x) + fabsf(kp[5] * mq.y) + fabsf(kp[6] * mq.z);
      float den = (mq.w + kp[3]) + 1e-6f;
      tau += 20.0f * 5.9604645e-08f * sp / den + 4e-7f * kr[t];
    }
    s_alt = ia; s_last = ib;
    s_hedge = ((kr[ia] - kr[ib]) < tau) ? 1 : 0;
  }
  __syncthreads();
  if (lane < RANKC) {
    const float* kp = kf + (size_t)(b * HW + kidx[lane]) * DD;
    float dot = 0.f;
#pragma unroll 8
    for (int d2 = 0; d2 < DD / 4; ++d2) {
      float4 k4 = ((const float4*)kp)[d2];
      float4 q4 = ((const float4*)qs)[d2];
      dot = fmaf(k4.x, q4.x, dot);
      dot = fmaf(k4.y, q4.y, dot);
      dot = fmaf(k4.z, q4.z, dot);
      dot = fmaf(k4.w, q4.w, dot);
    }
    lgt[lane] = dot * 0.0625f - kr[lane] / 0.1f;
  }
  __syncthreads();
  int ia = s_alt, ib = s_last, hedge = s_hedge;
  {
    float lgt_l = (lane < RANKC) ? lgt[lane] : -3.402823466e38f;
    float mv = (lane < RANKC && lane != ia) ? lgt_l : -3.402823466e38f;
#pragma unroll
    for (int off = 32; off; off >>= 1) mv = fmaxf(mv, __shfl_xor(mv, off));
    float e1 = (lane < RANKC && lane != ia) ? expf(lgt_l - mv) : 0.f;
    float z1 = e1;
#pragma unroll
    for (int off = 32; off; off >>= 1) z1 += __shfl_xor(z1, off);
    float w1 = e1 / z1;
    if (lane < RANKC) wgt[lane] = w1;
    if (hedge) {
      float mv2 = (lane < RANKC && lane != ib) ? lgt_l : -3.402823466e38f;
#pragma unroll
      for (int off = 32; off; off >>= 1) mv2 = fmaxf(mv2, __shfl_xor(mv2, off));
      float e2 = (lane < RANKC && lane != ib) ? expf(lgt_l - mv2) : 0.f;
      float z2 = e2;
#pragma unroll
      for (int off = 32; off; off >>= 1) z2 += __shfl_xor(z2, off);
      if (lane < RANKC) dw[lane] = w1 - e2 / z2;
    }
  }
  __syncthreads();
  float4 o = make_float4(0.f, 0.f, 0.f, 0.f);
  float4 od = make_float4(0.f, 0.f, 0.f, 0.f);
  const float* vb = vf + (size_t)b * HW * DD;
  for (int tt = 0; tt < RANKC; ++tt) {
    float wv = wgt[tt]; int j = kidx[tt];
    float4 vv = *(const float4*)(vb + (size_t)j * DD + lane * 4);
    o.x = fmaf(wv, vv.x, o.x);
    o.y = fmaf(wv, vv.y, o.y);
    o.z = fmaf(wv, vv.z, o.z);
    o.w = fmaf(wv, vv.w, o.w);
    if (hedge) {
      float dv = dw[tt];
      od.x = fmaf(dv, vv.x, od.x);
      od.y = fmaf(dv, vv.y, od.y);
      od.z = fmaf(dv, vv.z, od.z);
      od.w = fmaf(dv, vv.w, od.w);
    }
  }
  *(float4*)(fusedf + (size_t)tok * DD + lane * 4) = o;
  if (hedge) {
    *(float4*)(dfused + (size_t)tok * DD + lane * 4) = od;
    if (lane == 0) {
      int slot = atomicAdd(hcount, 1);
      if (slot < MAXH) hlist[slot] = tok;
    }
  }
}

// ---------------- kernel H1: per-slot gate norm, 16 c-chunk blocks per hedged token --------
__global__ __launch_bounds__(64) void hedge_norm(
    const float* __restrict__ Wo, const int* __restrict__ hcount,
    const int* __restrict__ hlist, const float* __restrict__ dfused,
    u32* __restrict__ gmax) {
  int slot = blockIdx.y;
  int cnt = *hcount; if (cnt > MAXH) cnt = MAXH;
  if (slot >= cnt) return;
  int tok = hlist[slot];
  __shared__ float dfl[DD];
  int t = threadIdx.x;  // 64 threads
  ((float4*)dfl)[t] = ((const float4*)(dfused + (size_t)tok * DD))[t];
  __syncthreads();
  int c = blockIdx.x * 64 + t;
  const float* wr = Wo + (size_t)c * DD;
  float dot = 0.f;
#pragma unroll 8
  for (int d = 0; d < DD; d += 4) {
    float4 w4 = *(const float4*)(wr + d);
    float4 f4 = *(const float4*)(dfl + d);
    dot = fmaf(w4.x, f4.x, dot);
    dot = fmaf(w4.y, f4.y, dot);
    dot = fmaf(w4.z, f4.z, dot);
    dot = fmaf(w4.w, f4.w, dot);
  }
  float am = fabsf(dot);
#pragma unroll
  for (int off = 32; off; off >>= 1) am = fmaxf(am, __shfl_xor(am, off));
  if (t == 0) atomicMax(&gmax[slot], __float_as_uint(am));  // nonneg floats: bit-monotone
}

// ---------------- kernel H2: apply hedge correction where gate passes ----------------
__global__ __launch_bounds__(256) void hedge_apply(
    const int* __restrict__ hcount, const int* __restrict__ hlist,
    const u32* __restrict__ gmax, const float* __restrict__ dfused,
    float* __restrict__ fusedf) {
  int slot = blockIdx.x;
  int cnt = *hcount; if (cnt > MAXH) cnt = MAXH;
  if (slot >= cnt) return;
  int tok = hlist[slot];
  if (__uint_as_float(gmax[slot]) <= GATE) {
    int t = threadIdx.x;
    fusedf[(size_t)tok * DD + t] -= 0.5f * dfused[(size_t)tok * DD + t];
  }
}

// ---------------- kernel 5: output projection, split-fp16 MFMA ----------------
__global__ __launch_bounds__(256) void out_mfma(
    const u16* __restrict__ woh, const u16* __restrict__ wol,
    const float* __restrict__ fusedf, const float* __restrict__ bo,
    float* __restrict__ out) {
  int itile = blockIdx.x, ctile = blockIdx.y, b = blockIdx.z;
  int i0 = itile * 128, c0 = ctile * 128;
  __shared__ u16 Bh[128 * 72], Bl[128 * 72];
  int tid = threadIdx.x, lane = tid & 63, wid = tid >> 6;
  int wm = (wid >> 1) * 64, wn = (wid & 1) * 64;
  f32x4 acc[4][4] = {};
  int rowA = lane & 15, kch = (lane >> 4) * 8;
  for (int ks = 0; ks < 4; ++ks) {
    int d0 = ks * 64;
#pragma unroll
    for (int p = 0; p < 4; ++p) {
      int rr = p * 32 + (tid >> 3);
      int dc = (tid & 7) * 8;
      const float* fp = &fusedf[(size_t)(b * HW + i0 + rr) * DD + d0 + dc];
      float4 f0 = *(const float4*)fp;
      float4 f1 = *(const float4*)(fp + 4);
      u16 h, l;
      split16(f0.x, h, l); Bh[rr * 72 + dc + 0] = h; Bl[rr * 72 + dc + 0] = l;
      split16(f0.y, h, l); Bh[rr * 72 + dc + 1] = h; Bl[rr * 72 + dc + 1] = l;
      split16(f0.z, h, l); Bh[rr * 72 + dc + 2] = h; Bl[rr * 72 + dc + 2] = l;
      split16(f0.w, h, l); Bh[rr * 72 + dc + 3] = h; Bl[rr * 72 + dc + 3] = l;
      split16(f1.x, h, l); Bh[rr * 72 + dc + 4] = h; Bl[rr * 72 + dc + 4] = l;
      split16(f1.y, h, l); Bh[rr * 72 + dc + 5] = h; Bl[rr * 72 + dc + 5] = l;
      split16(f1.z, h, l); Bh[rr * 72 + dc + 6] = h; Bl[rr * 72 + dc + 6] = l;
      split16(f1.w, h, l); Bh[rr * 72 + dc + 7] = h; Bl[rr * 72 + dc + 7] = l;
    }
    __syncthreads();
#pragma unroll
    for (int kk = 0; kk < 2; ++kk) {
      int ko = kk * 32 + kch;
      half8 ah[4], al[4], bh[4], bl[4];
#pragma unroll
      for (int mf = 0; mf < 4; ++mf) {
        size_t woff = (size_t)(c0 + wm + mf * 16 + rowA) * DD + d0 + ko;
        ah[mf] = *(const half8*)&woh[woff];
        al[mf] = *(const half8*)&wol[woff];
      }
#pragma unroll
      for (int nf = 0; nf < 4; ++nf) {
        bh[nf] = *(const half8*)&Bh[(wn + nf * 16 + rowA) * 72 + ko];
        bl[nf] = *(const half8*)&Bl[(wn + nf * 16 + rowA) * 72 + ko];
      }
#pragma unroll
      for (int mf = 0; mf < 4; ++mf)
#pragma unroll
        for (int nf = 0; nf < 4; ++nf) {
          acc[mf][nf] = __builtin_amdgcn_mfma_f32_16x16x32_f16(ah[mf], bh[nf], acc[mf][nf], 0, 0, 0);
          acc[mf][nf] = __builtin_amdgcn_mfma_f32_16x16x32_f16(ah[mf], bl[nf], acc[mf][nf], 0, 0, 0);
          acc[mf][nf] = __builtin_amdgcn_mfma_f32_16x16x32_f16(al[mf], bh[nf], acc[mf][nf], 0, 0, 0);
        }
    }
    __syncthreads();
  }
  int r4 = (lane >> 4) * 4, cold = lane & 15;
#pragma unroll
  for (int mf = 0; mf < 4; ++mf) {
#pragma unroll
    for (int r = 0; r < 4; ++r) {
      int crow = c0 + wm + mf * 16 + r4 + r;
      float bsv = bo[crow];
#pragma unroll
      for (int nf = 0; nf < 4; ++nf) {
        int icol = i0 + wn + nf * 16 + cold;
        out[(size_t)(b * CC + crow) * HW + icol] = acc[mf][nf][r] + bsv;
      }
    }
  }
}

extern "C" void kernel_launch(void* const* d_in, const int* in_sizes, int n_in,
                              void* d_out, int out_size, void* d_ws, size_t ws_size,
                              hipStream_t stream) {
  (void)in_sizes; (void)n_in; (void)out_size; (void)ws_size;
  const float* qmap = (const float*)d_in[0];
  const float* kvmap = (const float*)d_in[1];
  const float* pq = (const float*)d_in[2];
  const float* pk = (const float*)d_in[3];
  const float* lnqg = (const float*)d_in[4];
  const float* lnqb = (const float*)d_in[5];
  const float* lnkg = (const float*)d_in[6];
  const float* lnkb = (const float*)d_in[7];
  const float* Wq = (const float*)d_in[8];
  const float* bq = (const float*)d_in[9];
  const float* Wk = (const float*)d_in[10];
  const float* bk = (const float*)d_in[11];
  const float* Wv = (const float*)d_in[12];
  const float* bv = (const float*)d_in[13];
  const float* Wo = (const float*)d_in[14];
  const float* bo = (const float*)d_in[15];
  float* out = (float*)d_out;
  char* w = (char*)d_ws;
  size_t off = 0;
  auto take = [&](size_t n) { char* p = w + off; off += (n + 511) & ~(size_t)511; return p; };
  u16* wq_h = (u16*)take((size_t)DD * CC * 2);
  u16* wq_l = (u16*)take((size_t)DD * CC * 2);
  u16* wk_h = (u16*)take((size_t)DD * CC * 2);
  u16* wk_l = (u16*)take((size_t)DD * CC * 2);
  u16* wv_h = (u16*)take((size_t)DD * CC * 2);
  u16* wv_l = (u16*)take((size_t)DD * CC * 2);
  u16* wo_h = (u16*)take((size_t)CC * DD * 2);
  u16* wo_l = (u16*)take((size_t)CC * DD * 2);
  float* qray = (float*)take((size_t)NB * HW * 12 * 4);
  float* kray = (float*)take((size_t)NB * HW * 12 * 4);
  float* mu_q = (float*)take((size_t)NB * HW * 4);
  float* rs_q = (float*)take((size_t)NB * HW * 4);
  float* mu_k = (float*)take((size_t)NB * HW * 4);
  float* rs_k = (float*)take((size_t)NB * HW * 4);
  float* qf = (float*)take((size_t)NB * HW * DD * 4);
  float* kf = (float*)take((size_t)NB * HW * DD * 4);
  float* vf = (float*)take((size_t)NB * HW * DD * 4);
  float* fusedf = (float*)take((size_t)NB * HW * DD * 4);
  float* dfused = (float*)take((size_t)NB * HW * DD * 4);
  int* hcount = (int*)take(4);
  int* hlist = (int*)take((size_t)MAXH * 4);
  u32* gmax = (u32*)take((size_t)MAXH * 4);

  prep_weights<<<dim3(1024), 256, 0, stream>>>(Wq, Wk, Wv, Wo, wq_h, wq_l, wk_h, wk_l,
                                               wv_h, wv_l, wo_h, wo_l);
  prep_rays<<<dim3(36, 2), 256, 0, stream>>>(pq, pk, qray, kray);
  ln_stats<<<dim3(72, NB, 2), 256, 0, stream>>>(qmap, kvmap, mu_q, rs_q, mu_k, rs_k);
  hedge_init<<<dim3(2), 256, 0, stream>>>(hcount, gmax);
  proj_mfma<<<dim3(36, 3, NB), 256, 0, stream>>>(qmap, kvmap, lnqg, lnqb, lnkg, lnkb,
                                                 wq_h, wq_l, wk_h, wk_l, wv_h, wv_l,
                                                 bq, bk, bv, mu_q, rs_q, mu_k, rs_k,
                                                 qf, kf, vf);
  attn_f32<<<dim3(HW, NB), 64, 0, stream>>>(qf, kf, vf, qray, kray, fusedf, dfused,
                                            hcount, hlist);
  hedge_norm<<<dim3(16, MAXH), 64, 0, stream>>>(Wo, hcount, hlist, dfused, gmax);
  hedge_apply<<<dim3(MAXH), 256, 0, stream>>>(hcount, hlist, gmax, dfused, fusedf);
  out_mfma<<<dim3(18, 8, NB), 256, 0, stream>>>(wo_h, wo_l, fusedf, bo, out);
}